// Round 1
// baseline (833.868 us; speedup 1.0000x reference)
//
#include <hip/hip_runtime.h>
#include <hip/hip_bf16.h>

// Problem constants
#define S    2048
#define ND   128
#define NA   16
#define H    8
#define C    32
#define NH   24            // 3*H heads total
#define VD   128           // value dim per head
#define KQ_STRIDE (NH*C)   // 768 floats per row of K/Q
#define VAL_STRIDE (NH*VD) // 3072 floats per row of VAL

// ---------------------------------------------------------------------------
// Projection: K/Q from nodes (heads 0-7), aux (8-15), rot (16-23, no bias)
// Block handles 8 sequence rows; 1536 outputs (K+Q interleaved) per row.
// ---------------------------------------------------------------------------
__global__ __launch_bounds__(256) void proj_kq_kernel(
    const float* __restrict__ nodes, const float* __restrict__ aux,
    const float* __restrict__ rot,
    const float* __restrict__ Wn, const float* __restrict__ bn,
    const float* __restrict__ Wa, const float* __restrict__ ba,
    const float* __restrict__ Wr,
    float* __restrict__ K, float* __restrict__ Q) {
  const int i0 = blockIdx.x * 8;
  const int t  = threadIdx.x;

  __shared__ __align__(16) float sn[8][128];
  __shared__ __align__(16) float sa[8][16];
  __shared__ __align__(16) float sr[8][4];

  {
    int rr = t >> 5, e0 = (t & 31) * 4;
    *reinterpret_cast<float4*>(&sn[rr][e0]) =
        *reinterpret_cast<const float4*>(nodes + (size_t)(i0 + rr) * ND + e0);
  }
  if (t < 32) {
    int rr = t >> 2, e0 = (t & 3) * 4;
    *reinterpret_cast<float4*>(&sa[rr][e0]) =
        *reinterpret_cast<const float4*>(aux + (size_t)(i0 + rr) * NA + e0);
  }
  if (t < 8) {
    *reinterpret_cast<float4*>(&sr[t][0]) =
        *reinterpret_cast<const float4*>(rot + (size_t)t * 4 + (size_t)i0 * 4);
  }
  __syncthreads();

  for (int o = t; o < 1536; o += 256) {
    const int g    = o >> 9;        // 0 nodes, 1 aux, 2 rot
    const int w    = o & 511;       // row into the 512-row weight
    const int head = (g << 3) + (w >> 6);
    const int half = (w >> 5) & 1;  // 0 = k, 1 = q
    const int c    = w & 31;

    float accv[8];
    if (g == 0) {
      const float* wrow = Wn + (size_t)w * ND;
      const float bias = bn[w];
#pragma unroll
      for (int rr = 0; rr < 8; ++rr) accv[rr] = bias;
      for (int e = 0; e < ND; e += 4) {
        float4 wv = *reinterpret_cast<const float4*>(wrow + e);
#pragma unroll
        for (int rr = 0; rr < 8; ++rr) {
          accv[rr] += wv.x * sn[rr][e]   + wv.y * sn[rr][e+1]
                    + wv.z * sn[rr][e+2] + wv.w * sn[rr][e+3];
        }
      }
    } else if (g == 1) {
      const float* wrow = Wa + (size_t)w * NA;
      const float bias = ba[w];
#pragma unroll
      for (int rr = 0; rr < 8; ++rr) accv[rr] = bias;
#pragma unroll
      for (int e = 0; e < NA; e += 4) {
        float4 wv = *reinterpret_cast<const float4*>(wrow + e);
#pragma unroll
        for (int rr = 0; rr < 8; ++rr) {
          accv[rr] += wv.x * sa[rr][e]   + wv.y * sa[rr][e+1]
                    + wv.z * sa[rr][e+2] + wv.w * sa[rr][e+3];
        }
      }
    } else {
      float4 wv = *reinterpret_cast<const float4*>(Wr + (size_t)w * 4);
#pragma unroll
      for (int rr = 0; rr < 8; ++rr) {
        accv[rr] = wv.x * sr[rr][0] + wv.y * sr[rr][1]
                 + wv.z * sr[rr][2] + wv.w * sr[rr][3];
      }
    }

    float* dst = half ? Q : K;
#pragma unroll
    for (int rr = 0; rr < 8; ++rr) {
      dst[(size_t)(i0 + rr) * KQ_STRIDE + head * C + c] = accv[rr];
    }
  }
}

// ---------------------------------------------------------------------------
// Projection: VAL = nodes @ W_val.T + b_val  -> (S, 24, 128)
// ---------------------------------------------------------------------------
__global__ __launch_bounds__(256) void proj_val_kernel(
    const float* __restrict__ nodes, const float* __restrict__ Wv,
    const float* __restrict__ bv, float* __restrict__ VAL) {
  const int i0 = blockIdx.x * 8;
  const int t  = threadIdx.x;

  __shared__ __align__(16) float sn[8][128];
  {
    int rr = t >> 5, e0 = (t & 31) * 4;
    *reinterpret_cast<float4*>(&sn[rr][e0]) =
        *reinterpret_cast<const float4*>(nodes + (size_t)(i0 + rr) * ND + e0);
  }
  __syncthreads();

  for (int o = t; o < VAL_STRIDE; o += 256) {
    const float* wrow = Wv + (size_t)o * ND;
    const float bias = bv[o];
    float accv[8];
#pragma unroll
    for (int rr = 0; rr < 8; ++rr) accv[rr] = bias;
    for (int e = 0; e < ND; e += 4) {
      float4 wv = *reinterpret_cast<const float4*>(wrow + e);
#pragma unroll
      for (int rr = 0; rr < 8; ++rr) {
        accv[rr] += wv.x * sn[rr][e]   + wv.y * sn[rr][e+1]
                  + wv.z * sn[rr][e+2] + wv.w * sn[rr][e+3];
      }
    }
#pragma unroll
    for (int rr = 0; rr < 8; ++rr) {
      VAL[(size_t)(i0 + rr) * VAL_STRIDE + o] = accv[rr];
    }
  }
}

// ---------------------------------------------------------------------------
// Flash attention: block = (64 queries) x (1 head). Online softmax over keys.
// Score[i,j] = K[i,h,:] . Q[j,h,:]; squared for heads >= 16; * 1/sqrt(8).
// ATOMIC=false: write per-head partial O (divided by l) to OP.
// ATOMIC=true : atomicAdd directly into out (requires out zeroed).
// ---------------------------------------------------------------------------
template <bool ATOMIC>
__global__ __launch_bounds__(256) void attn_kernel(
    const float* __restrict__ K, const float* __restrict__ Q,
    const float* __restrict__ VAL, float* __restrict__ OP) {
  const int h    = blockIdx.y;
  const int i0   = blockIdx.x * 64;
  const int t    = threadIdx.x;
  const int r    = t & 63;   // query row within tile (== lane)
  const int quad = t >> 6;   // wave index: owns cols quad*16..+16, dims quad*32..+32
  const bool sq  = (h >= 16);
  const float scale = 0.3535533905932738f;  // 1/sqrt(8)

  __shared__ __align__(16) float Qs[64 * 32];      // [c][e]
  __shared__ __align__(16) float Vs[64 * 128];     // [c][d]
  __shared__ __align__(16) float Ps[64 * 65];      // [r][c] padded (+1)
  __shared__ float red[4 * 64];                    // [quad][r]

  // K row for this thread's query, in registers (32 floats)
  float kreg[32];
  {
    const float* kp = K + (size_t)(i0 + r) * KQ_STRIDE + h * C;
#pragma unroll
    for (int e = 0; e < 32; e += 4) {
      float4 v = *reinterpret_cast<const float4*>(kp + e);
      kreg[e] = v.x; kreg[e+1] = v.y; kreg[e+2] = v.z; kreg[e+3] = v.w;
    }
  }

  float m = -1e30f, l = 0.0f;
  float acc[32];
#pragma unroll
  for (int d = 0; d < 32; ++d) acc[d] = 0.0f;

  for (int j0 = 0; j0 < S; j0 += 64) {
    // --- stage Q tile (64 x 32) ---
    {
      int c = t >> 2, e0 = (t & 3) * 8;
      const float* qp = Q + (size_t)(j0 + c) * KQ_STRIDE + h * C + e0;
      *reinterpret_cast<float4*>(&Qs[c * 32 + e0])     = *reinterpret_cast<const float4*>(qp);
      *reinterpret_cast<float4*>(&Qs[c * 32 + e0 + 4]) = *reinterpret_cast<const float4*>(qp + 4);
    }
    // --- stage V tile (64 x 128) ---
    {
      int c = t >> 2, d0 = (t & 3) * 32;
      const float* vp = VAL + (size_t)(j0 + c) * VAL_STRIDE + h * VD + d0;
#pragma unroll
      for (int k = 0; k < 32; k += 4) {
        *reinterpret_cast<float4*>(&Vs[c * 128 + d0 + k]) =
            *reinterpret_cast<const float4*>(vp + k);
      }
    }
    __syncthreads();

    // --- scores: this thread covers 16 columns ---
    float s[16];
    float lmax = -1e30f;
#pragma unroll
    for (int cc = 0; cc < 16; ++cc) {
      const float* qrow = &Qs[(quad * 16 + cc) * 32];
      float v = 0.0f;
#pragma unroll
      for (int e = 0; e < 32; ++e) v += kreg[e] * qrow[e];
      if (sq) v = v * v;
      v *= scale;
      s[cc] = v;
      lmax = fmaxf(lmax, v);
    }
    red[quad * 64 + r] = lmax;
    __syncthreads();
    const float tmax = fmaxf(fmaxf(red[r], red[64 + r]),
                             fmaxf(red[128 + r], red[192 + r]));
    const float mnew = fmaxf(m, tmax);

    float lsum = 0.0f;
#pragma unroll
    for (int cc = 0; cc < 16; ++cc) {
      float p = __expf(s[cc] - mnew);
      Ps[r * 65 + quad * 16 + cc] = p;
      lsum += p;
    }
    __syncthreads();             // red(max) fully read; Ps visible after next sync
    red[quad * 64 + r] = lsum;
    __syncthreads();
    const float tsum = red[r] + red[64 + r] + red[128 + r] + red[192 + r];
    const float corr = __expf(m - mnew);
    l = l * corr + tsum;
    m = mnew;
#pragma unroll
    for (int d = 0; d < 32; ++d) acc[d] *= corr;

    // --- PV: acc[r][quad*32..+32] += sum_c P[r][c] * V[c][d] ---
    const float* vbase = &Vs[quad * 32];
#pragma unroll 4
    for (int c = 0; c < 64; ++c) {
      const float p = Ps[r * 65 + c];
      const float* vp = vbase + c * 128;
#pragma unroll
      for (int k = 0; k < 32; k += 4) {
        float4 v = *reinterpret_cast<const float4*>(vp + k);
        acc[k]     += p * v.x;
        acc[k + 1] += p * v.y;
        acc[k + 2] += p * v.z;
        acc[k + 3] += p * v.w;
      }
    }
    __syncthreads();   // protect Qs/Vs/Ps before next tile's stores
  }

  const float inv = 1.0f / l;
  if (ATOMIC) {
    float* op = OP + (size_t)(i0 + r) * VD + quad * 32;
#pragma unroll
    for (int k = 0; k < 32; ++k) atomicAdd(op + k, acc[k] * inv);
  } else {
    float* op = OP + (size_t)h * (S * VD) + (size_t)(i0 + r) * VD + quad * 32;
#pragma unroll
    for (int k = 0; k < 32; k += 4) {
      float4 v;
      v.x = acc[k] * inv; v.y = acc[k+1] * inv;
      v.z = acc[k+2] * inv; v.w = acc[k+3] * inv;
      *reinterpret_cast<float4*>(op + k) = v;
    }
  }
}

// Sum the 24 per-head partials into the final (S, 128) output.
__global__ __launch_bounds__(256) void reduce_out_kernel(
    const float* __restrict__ OP, float* __restrict__ out) {
  const int idx = blockIdx.x * 256 + threadIdx.x;  // 262144 total
  float s = 0.0f;
#pragma unroll
  for (int hh = 0; hh < NH; ++hh) s += OP[(size_t)hh * (S * VD) + idx];
  out[idx] = s;
}

extern "C" void kernel_launch(void* const* d_in, const int* in_sizes, int n_in,
                              void* d_out, int out_size, void* d_ws, size_t ws_size,
                              hipStream_t stream) {
  const float* nodes = (const float*)d_in[0];
  const float* aux   = (const float*)d_in[1];
  const float* rot   = (const float*)d_in[2];
  const float* Wn    = (const float*)d_in[3];
  const float* bn    = (const float*)d_in[4];
  const float* Wa    = (const float*)d_in[5];
  const float* ba    = (const float*)d_in[6];
  const float* Wr    = (const float*)d_in[7];
  const float* Wv    = (const float*)d_in[8];
  const float* bv    = (const float*)d_in[9];
  float* out = (float*)d_out;

  float* ws = (float*)d_ws;
  // ws layout (floats): K [2048*768], Q [2048*768], VAL [2048*3072], OP [24*2048*128]
  float* Kbuf = ws;
  float* Qbuf = ws + (size_t)S * KQ_STRIDE;                 // +1,572,864
  float* Vbuf = ws + (size_t)2 * S * KQ_STRIDE;             // +3,145,728
  float* OPbuf = ws + (size_t)2 * S * KQ_STRIDE + (size_t)S * VAL_STRIDE;

  const size_t need_full = ((size_t)2 * S * KQ_STRIDE + (size_t)S * VAL_STRIDE
                            + (size_t)NH * S * VD) * sizeof(float);  // ~60 MB
  const bool use_partials = (ws_size >= need_full);

  proj_kq_kernel<<<S / 8, 256, 0, stream>>>(nodes, aux, rot, Wn, bn, Wa, ba, Wr,
                                            Kbuf, Qbuf);
  proj_val_kernel<<<S / 8, 256, 0, stream>>>(nodes, Wv, bv, Vbuf);

  if (use_partials) {
    attn_kernel<false><<<dim3(S / 64, NH), 256, 0, stream>>>(Kbuf, Qbuf, Vbuf, OPbuf);
    reduce_out_kernel<<<(S * VD) / 256, 256, 0, stream>>>(OPbuf, out);
  } else {
    hipMemsetAsync(d_out, 0, (size_t)out_size * sizeof(float), stream);
    attn_kernel<true><<<dim3(S / 64, NH), 256, 0, stream>>>(Kbuf, Qbuf, Vbuf, out);
  }
}

// Round 2
// 236.606 us; speedup vs baseline: 3.5243x; 3.5243x over previous
//
#include <hip/hip_runtime.h>
#include <hip/hip_bf16.h>

// Problem constants
#define S    2048
#define ND   128
#define NA   16
#define H    8
#define C    32
#define NH   24            // 3*H heads total
#define VD   128           // value dim per head
#define KQ_STRIDE (NH*C)   // 768 elems per row of K/Q
#define VAL_STRIDE (NH*VD) // 3072 elems per row of VAL
#define SCALE 0.3535533905932738f  // 1/sqrt(8)

typedef __attribute__((ext_vector_type(8))) short short8;
typedef __attribute__((ext_vector_type(4))) float f32x4;

typedef __hip_bfloat16 bf16;

__device__ __forceinline__ short bf16_bits(float x) {
  bf16 h = __float2bfloat16(x);
  union { bf16 h; short s; } u; u.h = h; return u.s;
}

// ---------------------------------------------------------------------------
// Projection: K/Q (bf16) from nodes (heads 0-7), aux (8-15), rot (16-23).
// ---------------------------------------------------------------------------
__global__ __launch_bounds__(256) void proj_kq_kernel(
    const float* __restrict__ nodes, const float* __restrict__ aux,
    const float* __restrict__ rot,
    const float* __restrict__ Wn, const float* __restrict__ bn,
    const float* __restrict__ Wa, const float* __restrict__ ba,
    const float* __restrict__ Wr,
    bf16* __restrict__ K, bf16* __restrict__ Q) {
  const int i0 = blockIdx.x * 8;
  const int t  = threadIdx.x;

  __shared__ __align__(16) float sn[8][128];
  __shared__ __align__(16) float sa[8][16];
  __shared__ __align__(16) float sr[8][4];

  {
    int rr = t >> 5, e0 = (t & 31) * 4;
    *reinterpret_cast<float4*>(&sn[rr][e0]) =
        *reinterpret_cast<const float4*>(nodes + (size_t)(i0 + rr) * ND + e0);
  }
  if (t < 32) {
    int rr = t >> 2, e0 = (t & 3) * 4;
    *reinterpret_cast<float4*>(&sa[rr][e0]) =
        *reinterpret_cast<const float4*>(aux + (size_t)(i0 + rr) * NA + e0);
  }
  if (t < 8) {
    *reinterpret_cast<float4*>(&sr[t][0]) =
        *reinterpret_cast<const float4*>(rot + (size_t)(i0 + t) * 4);
  }
  __syncthreads();

  for (int o = t; o < 1536; o += 256) {
    const int g    = o >> 9;        // 0 nodes, 1 aux, 2 rot
    const int w    = o & 511;
    const int head = (g << 3) + (w >> 6);
    const int half = (w >> 5) & 1;  // 0 = k, 1 = q
    const int c    = w & 31;

    float accv[8];
    if (g == 0) {
      const float* wrow = Wn + (size_t)w * ND;
      const float bias = bn[w];
#pragma unroll
      for (int rr = 0; rr < 8; ++rr) accv[rr] = bias;
      for (int e = 0; e < ND; e += 4) {
        float4 wv = *reinterpret_cast<const float4*>(wrow + e);
#pragma unroll
        for (int rr = 0; rr < 8; ++rr) {
          accv[rr] += wv.x * sn[rr][e]   + wv.y * sn[rr][e+1]
                    + wv.z * sn[rr][e+2] + wv.w * sn[rr][e+3];
        }
      }
    } else if (g == 1) {
      const float* wrow = Wa + (size_t)w * NA;
      const float bias = ba[w];
#pragma unroll
      for (int rr = 0; rr < 8; ++rr) accv[rr] = bias;
#pragma unroll
      for (int e = 0; e < NA; e += 4) {
        float4 wv = *reinterpret_cast<const float4*>(wrow + e);
#pragma unroll
        for (int rr = 0; rr < 8; ++rr) {
          accv[rr] += wv.x * sa[rr][e]   + wv.y * sa[rr][e+1]
                    + wv.z * sa[rr][e+2] + wv.w * sa[rr][e+3];
        }
      }
    } else {
      float4 wv = *reinterpret_cast<const float4*>(Wr + (size_t)w * 4);
#pragma unroll
      for (int rr = 0; rr < 8; ++rr) {
        accv[rr] = wv.x * sr[rr][0] + wv.y * sr[rr][1]
                 + wv.z * sr[rr][2] + wv.w * sr[rr][3];
      }
    }

    bf16* dst = half ? Q : K;
#pragma unroll
    for (int rr = 0; rr < 8; ++rr) {
      dst[(size_t)(i0 + rr) * KQ_STRIDE + head * C + c] = __float2bfloat16(accv[rr]);
    }
  }
}

// ---------------------------------------------------------------------------
// Projection: VALt[h*128+d][i] bf16 (transposed so attention can stage
// V-tiles as [d][j] rows directly).
// ---------------------------------------------------------------------------
__global__ __launch_bounds__(256) void proj_val_kernel(
    const float* __restrict__ nodes, const float* __restrict__ Wv,
    const float* __restrict__ bv, bf16* __restrict__ VALt) {
  const int i0 = blockIdx.x * 8;
  const int t  = threadIdx.x;

  __shared__ __align__(16) float sn[8][128];
  {
    int rr = t >> 5, e0 = (t & 31) * 4;
    *reinterpret_cast<float4*>(&sn[rr][e0]) =
        *reinterpret_cast<const float4*>(nodes + (size_t)(i0 + rr) * ND + e0);
  }
  __syncthreads();

  for (int o = t; o < VAL_STRIDE; o += 256) {
    const float* wrow = Wv + (size_t)o * ND;
    const float bias = bv[o];
    float accv[8];
#pragma unroll
    for (int rr = 0; rr < 8; ++rr) accv[rr] = bias;
    for (int e = 0; e < ND; e += 4) {
      float4 wv = *reinterpret_cast<const float4*>(wrow + e);
#pragma unroll
      for (int rr = 0; rr < 8; ++rr) {
        accv[rr] += wv.x * sn[rr][e]   + wv.y * sn[rr][e+1]
                  + wv.z * sn[rr][e+2] + wv.w * sn[rr][e+3];
      }
    }
    short8 pack;
#pragma unroll
    for (int rr = 0; rr < 8; ++rr) pack[rr] = bf16_bits(accv[rr]);
    *reinterpret_cast<short8*>(VALt + (size_t)o * S + i0) = pack;
  }
}

// ---------------------------------------------------------------------------
// Rot-head rank-4 precompute: M_h = W_rk_h^T W_rq_h (4x4), G[i][h][:] = rot_i^T M_h
// ---------------------------------------------------------------------------
__global__ __launch_bounds__(256) void rotg_kernel(
    const float* __restrict__ rot, const float* __restrict__ Wr,
    float* __restrict__ G) {
  __shared__ float M[8][4][4];
  const int t = threadIdx.x;
  if (t < 128) {
    const int hl = t >> 4, a = (t >> 2) & 3, b = t & 3;
    float s = 0.0f;
#pragma unroll
    for (int c = 0; c < 32; ++c)
      s += Wr[(size_t)(hl * 64 + c) * 4 + a] * Wr[(size_t)(hl * 64 + 32 + c) * 4 + b];
    M[hl][a][b] = s;
  }
  __syncthreads();
  const int i  = blockIdx.x * 32 + (t >> 3);
  const int hl = t & 7;
  const float4 rv = *reinterpret_cast<const float4*>(rot + (size_t)i * 4);
  float4 g;
  g.x = rv.x * M[hl][0][0] + rv.y * M[hl][1][0] + rv.z * M[hl][2][0] + rv.w * M[hl][3][0];
  g.y = rv.x * M[hl][0][1] + rv.y * M[hl][1][1] + rv.z * M[hl][2][1] + rv.w * M[hl][3][1];
  g.z = rv.x * M[hl][0][2] + rv.y * M[hl][1][2] + rv.z * M[hl][2][2] + rv.w * M[hl][3][2];
  g.w = rv.x * M[hl][0][3] + rv.y * M[hl][1][3] + rv.z * M[hl][2][3] + rv.w * M[hl][3][3];
  *reinterpret_cast<float4*>(G + ((size_t)i * 8 + hl) * 4) = g;
}

// ---------------------------------------------------------------------------
// MFMA flash attention. Block = 4 waves x 16 query rows = 64 i-rows, 1 head.
// Scores for nodes/aux heads via mfma(K,Q); rot heads via exact fp32 rank-4.
// P round-trips through LDS (C/D layout -> A-frag layout). PV via mfma(P,V).
// k-map f(lane,j) = (lane>>4)*8+j used identically for every A and B frag,
// so a wrong guess of the HW k-map cancels (shared permutation of k).
// ---------------------------------------------------------------------------
template <bool ATOMIC>
__global__ __launch_bounds__(256) void attn_mfma_kernel(
    const bf16* __restrict__ Kb, const bf16* __restrict__ Qb,
    const bf16* __restrict__ Vt, const float* __restrict__ G,
    const float* __restrict__ rot, float* __restrict__ OP) {
  const int h    = blockIdx.y;
  const int i0   = blockIdx.x * 64;
  const int t    = threadIdx.x;
  const int lane = t & 63;
  const int w    = t >> 6;
  const int l15  = lane & 15;
  const int g4   = lane >> 4;
  const bool isrot = (h >= 16);

  __shared__ __align__(16) bf16 Vs[128][72];     // V-tile transposed [d][j], padded
  __shared__ __align__(16) bf16 Ps[4][16][72];   // per-wave P tile [i][j], padded

  short8 kfrag = {0, 0, 0, 0, 0, 0, 0, 0};
  float grow[4][4];
  if (!isrot) {
    kfrag = *reinterpret_cast<const short8*>(
        Kb + (size_t)(i0 + w * 16 + l15) * KQ_STRIDE + h * C + g4 * 8);
  } else {
    const int hl = h - 16;
#pragma unroll
    for (int r = 0; r < 4; ++r) {
      const float4 gv = *reinterpret_cast<const float4*>(
          G + ((size_t)(i0 + w * 16 + g4 * 4 + r) * 8 + hl) * 4);
      grow[r][0] = gv.x; grow[r][1] = gv.y; grow[r][2] = gv.z; grow[r][3] = gv.w;
    }
  }

  float m[4], l[4];
  f32x4 oacc[8];
#pragma unroll
  for (int r = 0; r < 4; ++r) { m[r] = -1e30f; l[r] = 0.0f; }
#pragma unroll
  for (int d = 0; d < 8; ++d) oacc[d] = (f32x4){0.f, 0.f, 0.f, 0.f};

  for (int j0 = 0; j0 < S; j0 += 64) {
    // ---- stage V tile: thread copies one half-row (32 bf16) ----
    {
      const int d  = t >> 1;
      const int jh = (t & 1) * 32;
      const bf16* src = Vt + ((size_t)h * VD + d) * S + j0 + jh;
      short8 v0 = *reinterpret_cast<const short8*>(src);
      short8 v1 = *reinterpret_cast<const short8*>(src + 8);
      short8 v2 = *reinterpret_cast<const short8*>(src + 16);
      short8 v3 = *reinterpret_cast<const short8*>(src + 24);
      *reinterpret_cast<short8*>(&Vs[d][jh])      = v0;
      *reinterpret_cast<short8*>(&Vs[d][jh + 8])  = v1;
      *reinterpret_cast<short8*>(&Vs[d][jh + 16]) = v2;
      *reinterpret_cast<short8*>(&Vs[d][jh + 24]) = v3;
    }
    __syncthreads();

    // ---- scores: 16 x 64 per wave, C/D layout row=(g4*4+r), col=(sub*16+l15)
    f32x4 sf[4];
    if (!isrot) {
#pragma unroll
      for (int sub = 0; sub < 4; ++sub) {
        short8 qf = *reinterpret_cast<const short8*>(
            Qb + (size_t)(j0 + sub * 16 + l15) * KQ_STRIDE + h * C + g4 * 8);
        f32x4 z = {0.f, 0.f, 0.f, 0.f};
        sf[sub] = __builtin_amdgcn_mfma_f32_16x16x32_bf16(kfrag, qf, z, 0, 0, 0);
#pragma unroll
        for (int r = 0; r < 4; ++r) sf[sub][r] *= SCALE;
      }
    } else {
#pragma unroll
      for (int sub = 0; sub < 4; ++sub) {
        const float4 rv = *reinterpret_cast<const float4*>(
            rot + (size_t)(j0 + sub * 16 + l15) * 4);
#pragma unroll
        for (int r = 0; r < 4; ++r) {
          float s = grow[r][0] * rv.x + grow[r][1] * rv.y
                  + grow[r][2] * rv.z + grow[r][3] * rv.w;
          sf[sub][r] = s * s * SCALE;
        }
      }
    }

    // ---- online softmax (rows reduced across the 16-lane group) ----
#pragma unroll
    for (int r = 0; r < 4; ++r) {
      float tm = fmaxf(fmaxf(sf[0][r], sf[1][r]), fmaxf(sf[2][r], sf[3][r]));
      tm = fmaxf(tm, __shfl_xor(tm, 1));
      tm = fmaxf(tm, __shfl_xor(tm, 2));
      tm = fmaxf(tm, __shfl_xor(tm, 4));
      tm = fmaxf(tm, __shfl_xor(tm, 8));
      const float mnew = fmaxf(m[r], tm);
      const float corr = __expf(m[r] - mnew);
      m[r] = mnew;
      float ls = 0.0f;
#pragma unroll
      for (int sub = 0; sub < 4; ++sub) {
        float p = __expf(sf[sub][r] - mnew);
        sf[sub][r] = p;
        ls += p;
      }
      ls += __shfl_xor(ls, 1);
      ls += __shfl_xor(ls, 2);
      ls += __shfl_xor(ls, 4);
      ls += __shfl_xor(ls, 8);
      l[r] = l[r] * corr + ls;
#pragma unroll
      for (int d = 0; d < 8; ++d) oacc[d][r] *= corr;
#pragma unroll
      for (int sub = 0; sub < 4; ++sub)
        Ps[w][g4 * 4 + r][sub * 16 + l15] = __float2bfloat16(sf[sub][r]);
    }

    // ---- PV: O[16 x 128] += P[16 x 64] * V[64 x 128] ----
#pragma unroll
    for (int kh = 0; kh < 2; ++kh) {
      const short8 pa = *reinterpret_cast<const short8*>(&Ps[w][l15][kh * 32 + g4 * 8]);
#pragma unroll
      for (int dsub = 0; dsub < 8; ++dsub) {
        const short8 vb = *reinterpret_cast<const short8*>(
            &Vs[dsub * 16 + l15][kh * 32 + g4 * 8]);
        oacc[dsub] = __builtin_amdgcn_mfma_f32_16x16x32_bf16(pa, vb, oacc[dsub], 0, 0, 0);
      }
    }
    __syncthreads();
  }

  float inv[4];
#pragma unroll
  for (int r = 0; r < 4; ++r) inv[r] = 1.0f / l[r];

  if (ATOMIC) {
#pragma unroll
    for (int dsub = 0; dsub < 8; ++dsub)
#pragma unroll
      for (int r = 0; r < 4; ++r)
        atomicAdd(OP + (size_t)(i0 + w * 16 + g4 * 4 + r) * VD + dsub * 16 + l15,
                  oacc[dsub][r] * inv[r]);
  } else {
    float* op = OP + (size_t)h * (S * VD);
#pragma unroll
    for (int dsub = 0; dsub < 8; ++dsub)
#pragma unroll
      for (int r = 0; r < 4; ++r)
        op[(size_t)(i0 + w * 16 + g4 * 4 + r) * VD + dsub * 16 + l15] =
            oacc[dsub][r] * inv[r];
  }
}

// Sum the 24 per-head partials into the final (S, 128) output.
__global__ __launch_bounds__(256) void reduce_out_kernel(
    const float* __restrict__ OP, float* __restrict__ out) {
  const int idx = blockIdx.x * 256 + threadIdx.x;
  float s = 0.0f;
#pragma unroll
  for (int hh = 0; hh < NH; ++hh) s += OP[(size_t)hh * (S * VD) + idx];
  out[idx] = s;
}

extern "C" void kernel_launch(void* const* d_in, const int* in_sizes, int n_in,
                              void* d_out, int out_size, void* d_ws, size_t ws_size,
                              hipStream_t stream) {
  const float* nodes = (const float*)d_in[0];
  const float* aux   = (const float*)d_in[1];
  const float* rot   = (const float*)d_in[2];
  const float* Wn    = (const float*)d_in[3];
  const float* bn    = (const float*)d_in[4];
  const float* Wa    = (const float*)d_in[5];
  const float* ba    = (const float*)d_in[6];
  const float* Wr    = (const float*)d_in[7];
  const float* Wv    = (const float*)d_in[8];
  const float* bv    = (const float*)d_in[9];
  float* out = (float*)d_out;

  char* ws = (char*)d_ws;
  // byte offsets
  const size_t off_Kb   = 0;                               // S*768 bf16 = 3 MB
  const size_t off_Qb   = off_Kb + (size_t)S * KQ_STRIDE * 2;
  const size_t off_Vt   = off_Qb + (size_t)S * KQ_STRIDE * 2;   // 24*128*S bf16
  const size_t off_G    = off_Vt + (size_t)NH * VD * S * 2;     // S*8*4 f32
  const size_t off_OP   = off_G + (size_t)S * 8 * 4 * 4;        // 24*S*128 f32
  const size_t need     = off_OP + (size_t)NH * S * VD * 4;

  bf16*  Kb = (bf16*)(ws + off_Kb);
  bf16*  Qb = (bf16*)(ws + off_Qb);
  bf16*  Vt = (bf16*)(ws + off_Vt);
  float* G  = (float*)(ws + off_G);
  float* OP = (float*)(ws + off_OP);

  proj_kq_kernel<<<S / 8, 256, 0, stream>>>(nodes, aux, rot, Wn, bn, Wa, ba, Wr,
                                            Kb, Qb);
  proj_val_kernel<<<S / 8, 256, 0, stream>>>(nodes, Wv, bv, Vt);
  rotg_kernel<<<S / 32, 256, 0, stream>>>(rot, Wr, G);

  if (ws_size >= need) {
    attn_mfma_kernel<false><<<dim3(S / 64, NH), 256, 0, stream>>>(Kb, Qb, Vt, G,
                                                                  rot, OP);
    reduce_out_kernel<<<(S * VD) / 256, 256, 0, stream>>>(OP, out);
  } else {
    hipMemsetAsync(d_out, 0, (size_t)out_size * sizeof(float), stream);
    attn_mfma_kernel<true><<<dim3(S / 64, NH), 256, 0, stream>>>(Kb, Qb, Vt, G,
                                                                 rot, out);
  }
}

// Round 3
// 141.104 us; speedup vs baseline: 5.9096x; 1.6768x over previous
//
#include <hip/hip_runtime.h>
#include <hip/hip_bf16.h>

// Problem constants
#define S    2048
#define ND   128
#define NA   16
#define H    8
#define C    32
#define NH   24            // 3*H heads total
#define VD   128           // value dim per head
#define KQ_STRIDE (NH*C)   // 768 elems per row of K/Q
#define VAL_STRIDE (NH*VD) // 3072 elems per row of VAL
#define SCALE 0.3535533905932738f  // 1/sqrt(8)

// bf16 conversion-buffer element counts (flat regions in ws)
#define AN_SZ (S*ND)        // nodes bf16          262144
#define AA_SZ (S*32)        // aux  bf16 K-pad 32   65536
#define BN_SZ (512*ND)      // Wn   bf16            65536
#define BA_SZ (512*32)      // Wa   bf16 K-pad 32   16384
#define BV_SZ (3072*ND)     // Wv   bf16           393216
#define CONV_TOTAL (AN_SZ + AA_SZ + BN_SZ + BA_SZ + BV_SZ)  // 802816

typedef __attribute__((ext_vector_type(8))) short short8;
typedef __attribute__((ext_vector_type(4))) short s4v;
typedef __attribute__((ext_vector_type(4))) float f32x4;

typedef __hip_bfloat16 bf16;

__device__ __forceinline__ short bf16_bits(float x) {
  bf16 h = __float2bfloat16(x);
  union { bf16 h; short s; } u; u.h = h; return u.s;
}

// ---------------------------------------------------------------------------
// Cast nodes/Wn/Wv to bf16; zero-pad aux/Wa from K=16 to K=32 (exact under
// MFMA: padded zeros contribute nothing). One flat output space.
// ---------------------------------------------------------------------------
__global__ __launch_bounds__(256) void convert_kernel(
    const float* __restrict__ nodes, const float* __restrict__ aux,
    const float* __restrict__ Wn, const float* __restrict__ Wa,
    const float* __restrict__ Wv, bf16* __restrict__ out) {
  const int base = (blockIdx.x * 256 + threadIdx.x) * 4;
#pragma unroll
  for (int u = 0; u < 4; ++u) {
    const int idx = base + u;
    int k = idx;
    float v;
    if (k < AN_SZ) {
      v = nodes[k];
    } else if ((k -= AN_SZ) < AA_SZ) {
      const int ccol = k & 31;
      v = (ccol < 16) ? aux[(size_t)(k >> 5) * NA + ccol] : 0.0f;
    } else if ((k -= AA_SZ) < BN_SZ) {
      v = Wn[k];
    } else if ((k -= BN_SZ) < BA_SZ) {
      const int ccol = k & 31;
      v = (ccol < 16) ? Wa[(size_t)(k >> 5) * NA + ccol] : 0.0f;
    } else {
      v = Wv[k - BA_SZ];
    }
    out[idx] = __float2bfloat16(v);
  }
}

// ---------------------------------------------------------------------------
// MFMA projection GEMM: C[i][o] = sum_k A[i][k]*B[o][k] + bias[o].
// A: [2048][KE] bf16, B: [N][KE] bf16, both row-major; frags straight from
// L2 (no LDS; B panel is 16 KB and fully cached). Block = 64 i x 64 o,
// 4 waves each owning 16 i-rows. Frag k-map identical for A and B so any
// permutation of k cancels (same convention the verified attn kernel uses).
// EPI 0: nodes k/q (heads 0-7)   -> d0=K, d1=Q, interleaved [i][head*32+c]
// EPI 1: aux   k/q (heads 8-15)  -> d0=K, d1=Q
// EPI 2: val                     -> d0=VALt[o][i] (transposed), 8B stores
// ---------------------------------------------------------------------------
template <int KE, int EPI>
__global__ __launch_bounds__(256) void gemm_proj_kernel(
    const bf16* __restrict__ A, const bf16* __restrict__ B,
    const float* __restrict__ bias,
    bf16* __restrict__ d0, bf16* __restrict__ d1) {
  const int t = threadIdx.x;
  const int lane = t & 63;
  const int w = t >> 6;
  const int l15 = lane & 15, g4 = lane >> 4;
  const int i0 = blockIdx.x * 64 + w * 16;   // wave's A-row base
  const int o0 = blockIdx.y * 64;            // block's B-row base

  f32x4 acc[4];
#pragma unroll
  for (int s = 0; s < 4; ++s) acc[s] = (f32x4){0.f, 0.f, 0.f, 0.f};

  const bf16* arow = A + (size_t)(i0 + l15) * KE + g4 * 8;
  const bf16* brow = B + (size_t)(o0 + l15) * KE + g4 * 8;
#pragma unroll
  for (int ks = 0; ks < KE / 32; ++ks) {
    const short8 af = *reinterpret_cast<const short8*>(arow + ks * 32);
#pragma unroll
    for (int s = 0; s < 4; ++s) {
      const short8 bfr = *reinterpret_cast<const short8*>(
          brow + (size_t)s * 16 * KE + ks * 32);
      acc[s] = __builtin_amdgcn_mfma_f32_16x16x32_bf16(af, bfr, acc[s], 0, 0, 0);
    }
  }

  // C/D layout: lane (l15,g4) holds C[i0+g4*4+r][o0+s*16+l15], r=0..3
#pragma unroll
  for (int s = 0; s < 4; ++s) {
    const int o = o0 + s * 16 + l15;
    const float bb = bias[o];
    if (EPI == 2) {
      s4v pk;
#pragma unroll
      for (int r = 0; r < 4; ++r) pk[r] = bf16_bits(acc[s][r] + bb);
      *reinterpret_cast<s4v*>(d0 + (size_t)o * S + i0 + g4 * 4) = pk;
    } else {
      const int head = (EPI == 0 ? 0 : 8) + (o >> 6);
      const int half = (o >> 5) & 1;
      const int c = o & 31;
      bf16* dst = half ? d1 : d0;
#pragma unroll
      for (int r = 0; r < 4; ++r)
        dst[(size_t)(i0 + g4 * 4 + r) * KQ_STRIDE + head * C + c] =
            __float2bfloat16(acc[s][r] + bb);
    }
  }
}

// ---------------------------------------------------------------------------
// Rot-head rank-4 precompute: M_h = W_rk_h^T W_rq_h (4x4), G[i][h][:] = rot_i^T M_h
// ---------------------------------------------------------------------------
__global__ __launch_bounds__(256) void rotg_kernel(
    const float* __restrict__ rot, const float* __restrict__ Wr,
    float* __restrict__ G) {
  __shared__ float M[8][4][4];
  const int t = threadIdx.x;
  if (t < 128) {
    const int hl = t >> 4, a = (t >> 2) & 3, b = t & 3;
    float s = 0.0f;
#pragma unroll
    for (int c = 0; c < 32; ++c)
      s += Wr[(size_t)(hl * 64 + c) * 4 + a] * Wr[(size_t)(hl * 64 + 32 + c) * 4 + b];
    M[hl][a][b] = s;
  }
  __syncthreads();
  const int i  = blockIdx.x * 32 + (t >> 3);
  const int hl = t & 7;
  const float4 rv = *reinterpret_cast<const float4*>(rot + (size_t)i * 4);
  float4 g;
  g.x = rv.x * M[hl][0][0] + rv.y * M[hl][1][0] + rv.z * M[hl][2][0] + rv.w * M[hl][3][0];
  g.y = rv.x * M[hl][0][1] + rv.y * M[hl][1][1] + rv.z * M[hl][2][1] + rv.w * M[hl][3][1];
  g.z = rv.x * M[hl][0][2] + rv.y * M[hl][1][2] + rv.z * M[hl][2][2] + rv.w * M[hl][3][2];
  g.w = rv.x * M[hl][0][3] + rv.y * M[hl][1][3] + rv.z * M[hl][2][3] + rv.w * M[hl][3][3];
  *reinterpret_cast<float4*>(G + ((size_t)i * 8 + hl) * 4) = g;
}

// ---------------------------------------------------------------------------
// MFMA flash attention. Block = 4 waves x 16 query rows = 64 i-rows, 1 head.
// Scores for nodes/aux heads via mfma(K,Q); rot heads via exact fp32 rank-4.
// ---------------------------------------------------------------------------
template <bool ATOMIC>
__global__ __launch_bounds__(256) void attn_mfma_kernel(
    const bf16* __restrict__ Kb, const bf16* __restrict__ Qb,
    const bf16* __restrict__ Vt, const float* __restrict__ G,
    const float* __restrict__ rot, float* __restrict__ OP) {
  const int h    = blockIdx.y;
  const int i0   = blockIdx.x * 64;
  const int t    = threadIdx.x;
  const int lane = t & 63;
  const int w    = t >> 6;
  const int l15  = lane & 15;
  const int g4   = lane >> 4;
  const bool isrot = (h >= 16);

  __shared__ __align__(16) bf16 Vs[128][72];     // V-tile transposed [d][j], padded
  __shared__ __align__(16) bf16 Ps[4][16][72];   // per-wave P tile [i][j], padded

  short8 kfrag = {0, 0, 0, 0, 0, 0, 0, 0};
  float grow[4][4];
  if (!isrot) {
    kfrag = *reinterpret_cast<const short8*>(
        Kb + (size_t)(i0 + w * 16 + l15) * KQ_STRIDE + h * C + g4 * 8);
  } else {
    const int hl = h - 16;
#pragma unroll
    for (int r = 0; r < 4; ++r) {
      const float4 gv = *reinterpret_cast<const float4*>(
          G + ((size_t)(i0 + w * 16 + g4 * 4 + r) * 8 + hl) * 4);
      grow[r][0] = gv.x; grow[r][1] = gv.y; grow[r][2] = gv.z; grow[r][3] = gv.w;
    }
  }

  float m[4], l[4];
  f32x4 oacc[8];
#pragma unroll
  for (int r = 0; r < 4; ++r) { m[r] = -1e30f; l[r] = 0.0f; }
#pragma unroll
  for (int d = 0; d < 8; ++d) oacc[d] = (f32x4){0.f, 0.f, 0.f, 0.f};

  for (int j0 = 0; j0 < S; j0 += 64) {
    // ---- stage V tile: thread copies one half-row (32 bf16) ----
    {
      const int d  = t >> 1;
      const int jh = (t & 1) * 32;
      const bf16* src = Vt + ((size_t)h * VD + d) * S + j0 + jh;
      short8 v0 = *reinterpret_cast<const short8*>(src);
      short8 v1 = *reinterpret_cast<const short8*>(src + 8);
      short8 v2 = *reinterpret_cast<const short8*>(src + 16);
      short8 v3 = *reinterpret_cast<const short8*>(src + 24);
      *reinterpret_cast<short8*>(&Vs[d][jh])      = v0;
      *reinterpret_cast<short8*>(&Vs[d][jh + 8])  = v1;
      *reinterpret_cast<short8*>(&Vs[d][jh + 16]) = v2;
      *reinterpret_cast<short8*>(&Vs[d][jh + 24]) = v3;
    }
    __syncthreads();

    // ---- scores: 16 x 64 per wave, C/D layout row=(g4*4+r), col=(sub*16+l15)
    f32x4 sf[4];
    if (!isrot) {
#pragma unroll
      for (int sub = 0; sub < 4; ++sub) {
        short8 qf = *reinterpret_cast<const short8*>(
            Qb + (size_t)(j0 + sub * 16 + l15) * KQ_STRIDE + h * C + g4 * 8);
        f32x4 z = {0.f, 0.f, 0.f, 0.f};
        sf[sub] = __builtin_amdgcn_mfma_f32_16x16x32_bf16(kfrag, qf, z, 0, 0, 0);
#pragma unroll
        for (int r = 0; r < 4; ++r) sf[sub][r] *= SCALE;
      }
    } else {
#pragma unroll
      for (int sub = 0; sub < 4; ++sub) {
        const float4 rv = *reinterpret_cast<const float4*>(
            rot + (size_t)(j0 + sub * 16 + l15) * 4);
#pragma unroll
        for (int r = 0; r < 4; ++r) {
          float s = grow[r][0] * rv.x + grow[r][1] * rv.y
                  + grow[r][2] * rv.z + grow[r][3] * rv.w;
          sf[sub][r] = s * s * SCALE;
        }
      }
    }

    // ---- online softmax (rows reduced across the 16-lane group) ----
#pragma unroll
    for (int r = 0; r < 4; ++r) {
      float tm = fmaxf(fmaxf(sf[0][r], sf[1][r]), fmaxf(sf[2][r], sf[3][r]));
      tm = fmaxf(tm, __shfl_xor(tm, 1));
      tm = fmaxf(tm, __shfl_xor(tm, 2));
      tm = fmaxf(tm, __shfl_xor(tm, 4));
      tm = fmaxf(tm, __shfl_xor(tm, 8));
      const float mnew = fmaxf(m[r], tm);
      const float corr = __expf(m[r] - mnew);
      m[r] = mnew;
      float ls = 0.0f;
#pragma unroll
      for (int sub = 0; sub < 4; ++sub) {
        float p = __expf(sf[sub][r] - mnew);
        sf[sub][r] = p;
        ls += p;
      }
      ls += __shfl_xor(ls, 1);
      ls += __shfl_xor(ls, 2);
      ls += __shfl_xor(ls, 4);
      ls += __shfl_xor(ls, 8);
      l[r] = l[r] * corr + ls;
#pragma unroll
      for (int d = 0; d < 8; ++d) oacc[d][r] *= corr;
#pragma unroll
      for (int sub = 0; sub < 4; ++sub)
        Ps[w][g4 * 4 + r][sub * 16 + l15] = __float2bfloat16(sf[sub][r]);
    }

    // ---- PV: O[16 x 128] += P[16 x 64] * V[64 x 128] ----
#pragma unroll
    for (int kh = 0; kh < 2; ++kh) {
      const short8 pa = *reinterpret_cast<const short8*>(&Ps[w][l15][kh * 32 + g4 * 8]);
#pragma unroll
      for (int dsub = 0; dsub < 8; ++dsub) {
        const short8 vb = *reinterpret_cast<const short8*>(
            &Vs[dsub * 16 + l15][kh * 32 + g4 * 8]);
        oacc[dsub] = __builtin_amdgcn_mfma_f32_16x16x32_bf16(pa, vb, oacc[dsub], 0, 0, 0);
      }
    }
    __syncthreads();
  }

  float inv[4];
#pragma unroll
  for (int r = 0; r < 4; ++r) inv[r] = 1.0f / l[r];

  if (ATOMIC) {
#pragma unroll
    for (int dsub = 0; dsub < 8; ++dsub)
#pragma unroll
      for (int r = 0; r < 4; ++r)
        atomicAdd(OP + (size_t)(i0 + w * 16 + g4 * 4 + r) * VD + dsub * 16 + l15,
                  oacc[dsub][r] * inv[r]);
  } else {
    float* op = OP + (size_t)h * (S * VD);
#pragma unroll
    for (int dsub = 0; dsub < 8; ++dsub)
#pragma unroll
      for (int r = 0; r < 4; ++r)
        op[(size_t)(i0 + w * 16 + g4 * 4 + r) * VD + dsub * 16 + l15] =
            oacc[dsub][r] * inv[r];
  }
}

// Sum the 24 per-head partials into the final (S, 128) output.
__global__ __launch_bounds__(256) void reduce_out_kernel(
    const float* __restrict__ OP, float* __restrict__ out) {
  const int idx = blockIdx.x * 256 + threadIdx.x;
  float s = 0.0f;
#pragma unroll
  for (int hh = 0; hh < NH; ++hh) s += OP[(size_t)hh * (S * VD) + idx];
  out[idx] = s;
}

extern "C" void kernel_launch(void* const* d_in, const int* in_sizes, int n_in,
                              void* d_out, int out_size, void* d_ws, size_t ws_size,
                              hipStream_t stream) {
  const float* nodes = (const float*)d_in[0];
  const float* aux   = (const float*)d_in[1];
  const float* rot   = (const float*)d_in[2];
  const float* Wn    = (const float*)d_in[3];
  const float* bn    = (const float*)d_in[4];
  const float* Wa    = (const float*)d_in[5];
  const float* ba    = (const float*)d_in[6];
  const float* Wr    = (const float*)d_in[7];
  const float* Wv    = (const float*)d_in[8];
  const float* bv    = (const float*)d_in[9];
  float* out = (float*)d_out;

  char* ws = (char*)d_ws;
  // byte offsets
  const size_t off_conv = 0;                                    // bf16 x 802816
  const size_t off_Kb   = off_conv + (size_t)CONV_TOTAL * 2;    // S*768 bf16
  const size_t off_Qb   = off_Kb + (size_t)S * KQ_STRIDE * 2;
  const size_t off_Vt   = off_Qb + (size_t)S * KQ_STRIDE * 2;   // 24*128*S bf16
  const size_t off_G    = off_Vt + (size_t)NH * VD * S * 2;     // S*8*4 f32
  const size_t off_OP   = off_G + (size_t)S * 8 * 4 * 4;        // 24*S*128 f32
  const size_t need     = off_OP + (size_t)NH * S * VD * 4;     // ~46 MB
  const size_t need_min = off_OP;                               // ~21 MB

  bf16* convb = (bf16*)(ws + off_conv);
  bf16* An = convb;
  bf16* Aa = convb + AN_SZ;
  bf16* Bn = convb + AN_SZ + AA_SZ;
  bf16* Ba = convb + AN_SZ + AA_SZ + BN_SZ;
  bf16* Bv = convb + AN_SZ + AA_SZ + BN_SZ + BA_SZ;
  bf16*  Kb = (bf16*)(ws + off_Kb);
  bf16*  Qb = (bf16*)(ws + off_Qb);
  bf16*  Vt = (bf16*)(ws + off_Vt);
  float* G  = (float*)(ws + off_G);
  float* OP = (float*)(ws + off_OP);

  convert_kernel<<<CONV_TOTAL / 1024, 256, 0, stream>>>(nodes, aux, Wn, Wa, Wv, convb);
  rotg_kernel<<<S / 32, 256, 0, stream>>>(rot, Wr, G);

  gemm_proj_kernel<128, 0><<<dim3(S / 64, 512 / 64), 256, 0, stream>>>(
      An, Bn, bn, Kb, Qb);
  gemm_proj_kernel<32, 1><<<dim3(S / 64, 512 / 64), 256, 0, stream>>>(
      Aa, Ba, ba, Kb, Qb);
  gemm_proj_kernel<128, 2><<<dim3(S / 64, 3072 / 64), 256, 0, stream>>>(
      An, Bv, bv, Vt, nullptr);

  if (ws_size >= need) {
    attn_mfma_kernel<false><<<dim3(S / 64, NH), 256, 0, stream>>>(Kb, Qb, Vt, G,
                                                                  rot, OP);
    reduce_out_kernel<<<(S * VD) / 256, 256, 0, stream>>>(OP, out);
  } else {
    hipMemsetAsync(d_out, 0, (size_t)out_size * sizeof(float), stream);
    attn_mfma_kernel<true><<<dim3(S / 64, NH), 256, 0, stream>>>(Kb, Qb, Vt, G,
                                                                 rot, out);
  }
}